// Round 9
// baseline (8442.102 us; speedup 1.0000x reference)
//
#include <hip/hip_runtime.h>

#define N_NODES 8192
#define NNZV    262144
#define E_EDGES 32768
#define PSI     64
#define NTHR    256
#define EDGE_CHUNK 1024
#define N_TICKETS (NNZV / EDGE_CHUNK)    // 256
#define EPT (EDGE_CHUNK / NTHR)          // 4 edges per thread
#define GATHER_BLKS (E_EDGES / NTHR)     // 128

typedef float f32x4 __attribute__((ext_vector_type(4)));

struct Ctl { int ticket; int edge_done; int flag_s2; int rows_done; int pad[12]; };

// Single fused kernel, ordinary launch (graph-capture safe), no grid.sync.
//  blocks [0, 8192): row blocks. Pre-issue own adj row (NT loads) + square,
//    opportunistically steal edge-MLP chunks via ticket counter, then poll
//    s2-ready flag, finish dot product, write r, bump rows_done.
//  blocks [8192, 8320): gather blocks. Poll rows_done==8192, then out[e]=r[src[e]].
// Deadlock-free: edge work is done by whichever blocks grab tickets (they are
// running by construction); flag set by the 256th chunk-finisher; consumers
// only poll flags that running blocks are guaranteed to set.
__global__ void fused(const int* __restrict__ col, const float* __restrict__ values,
                      const float* __restrict__ adj, const int* __restrict__ src,
                      const float* __restrict__ w1e, const float* __restrict__ b1e,
                      const float* __restrict__ w2e, const float* __restrict__ b2e,
                      const float* __restrict__ w1n, const float* __restrict__ b1n,
                      const float* __restrict__ w2n, const float* __restrict__ b2n,
                      float* __restrict__ agg, float* __restrict__ s2,
                      float* __restrict__ r, Ctl* __restrict__ ctl,
                      float* __restrict__ out)
{
    const int t = threadIdx.x;
    const int bid = blockIdx.x;

    // ---------------- gather blocks ----------------
    if (bid >= N_NODES) {
        __shared__ int go;
        if (t == 0) {
            while (__hip_atomic_load(&ctl->rows_done, __ATOMIC_ACQUIRE,
                                     __HIP_MEMORY_SCOPE_AGENT) < N_NODES)
                __builtin_amdgcn_s_sleep(32);
            go = 1;
        }
        __syncthreads();
        (void)go;
        int e = (bid - N_NODES) * NTHR + t;
        out[e] = r[src[e]];
        return;
    }

    // ---------------- row blocks ----------------
    // 1) pre-issue the full adj row: 8 NT f32x4 loads/lane, square in place.
    const f32x4* arow = (const f32x4*)(adj + (size_t)bid * N_NODES);
    f32x4 a[8];
    #pragma unroll
    for (int j = 0; j < 8; ++j) a[j] = __builtin_nontemporal_load(&arow[t + j * NTHR]);
    #pragma unroll
    for (int j = 0; j < 8; ++j) a[j] *= a[j];

    // 2) opportunistic edge-MLP work-stealing.
    __shared__ float w[3 * PSI];
    __shared__ int sh_tk, sh_done;
    bool havew = false;
    for (;;) {
        if (t == 0) sh_tk = atomicAdd(&ctl->ticket, 1);
        __syncthreads();
        const int tk = sh_tk;
        __syncthreads();
        if (tk >= N_TICKETS) break;
        if (!havew) {
            if (t < PSI) { w[t] = w1e[t]; w[PSI + t] = b1e[t]; w[2 * PSI + t] = w2e[t]; }
            __syncthreads();
            havew = true;
        }
        const float fb = b2e[0];
        #pragma unroll
        for (int q = 0; q < EPT; ++q) {
            const int e = tk * EDGE_CHUNK + q * NTHR + t;
            const float v = values[e];
            float f = fb;
            #pragma unroll
            for (int j = 0; j < PSI; ++j) {
                float h = fmaf(v, w[j], w[PSI + j]);
                f += (h > 0.f ? h * w[2 * PSI + j] : 0.f);
            }
            atomicAdd(&agg[col[e]], f);
        }
        __threadfence();
        __syncthreads();
        if (t == 0)
            sh_done = __hip_atomic_fetch_add(&ctl->edge_done, 1, __ATOMIC_ACQ_REL,
                                             __HIP_MEMORY_SCOPE_AGENT) + 1;
        __syncthreads();
        if (sh_done == N_TICKETS) {
            // last chunk-finisher computes the node MLP -> s2, sets flag
            if (t < PSI) { w[t] = w1n[t]; w[PSI + t] = b1n[t]; w[2 * PSI + t] = w2n[t]; }
            __syncthreads();
            const float b2 = b2n[0];
            for (int n = t; n < N_NODES; n += NTHR) {
                const float av = agg[n];
                float s = b2;
                #pragma unroll
                for (int j = 0; j < PSI; ++j) {
                    float h = fmaf(av, w[j], w[PSI + j]);
                    s += (h > 0.f ? h * w[2 * PSI + j] : 0.f);
                }
                s2[n] = s * s;
            }
            __threadfence();
            __syncthreads();
            if (t == 0)
                __hip_atomic_store(&ctl->flag_s2, 1, __ATOMIC_RELEASE,
                                   __HIP_MEMORY_SCOPE_AGENT);
        }
        __syncthreads();
    }

    // 3) wait for s2 (t0 polls; acquire invalidates L1 for the whole CU).
    __shared__ int sready;
    if (t == 0) {
        while (!__hip_atomic_load(&ctl->flag_s2, __ATOMIC_ACQUIRE,
                                  __HIP_MEMORY_SCOPE_AGENT))
            __builtin_amdgcn_s_sleep(16);
        sready = 1;
    }
    __syncthreads();
    (void)sready;

    // 4) finish: acc = sum a2[j] . s2[j]
    const f32x4* s4 = (const f32x4*)s2;
    float acc = 0.f;
    #pragma unroll
    for (int j = 0; j < 8; ++j) {
        f32x4 s = s4[t + j * NTHR];
        f32x4 p = a[j] * s;
        acc += p.x + p.y + p.z + p.w;
    }
    #pragma unroll
    for (int off = 32; off > 0; off >>= 1) acc += __shfl_xor(acc, off, 64);
    __shared__ float part[4];
    const int lane = t & 63, wid = t >> 6;
    if (lane == 0) part[wid] = acc;
    __syncthreads();
    if (t == 0) {
        r[bid] = part[0] + part[1] + part[2] + part[3];
        __hip_atomic_fetch_add(&ctl->rows_done, 1, __ATOMIC_RELEASE,
                               __HIP_MEMORY_SCOPE_AGENT);
    }
}

extern "C" void kernel_launch(void* const* d_in, const int* in_sizes, int n_in,
                              void* d_out, int out_size, void* d_ws, size_t ws_size,
                              hipStream_t stream) {
    const int*   col       = (const int*)d_in[0];
    const float* values    = (const float*)d_in[1];
    const float* adj       = (const float*)d_in[2];
    const int*   src_nodes = (const int*)d_in[3];
    const float* w1e = (const float*)d_in[4];
    const float* b1e = (const float*)d_in[5];
    const float* w2e = (const float*)d_in[6];
    const float* b2e = (const float*)d_in[7];
    const float* w1n = (const float*)d_in[8];
    const float* b1n = (const float*)d_in[9];
    const float* w2n = (const float*)d_in[10];
    const float* b2n = (const float*)d_in[11];
    float* outp = (float*)d_out;

    // d_ws layout: [agg 8192 f32][Ctl][s2 8192 f32][r 8192 f32]
    float* agg = (float*)d_ws;
    Ctl*   ctl = (Ctl*)(agg + N_NODES);
    float* s2g = (float*)(ctl + 1);
    float* r   = s2g + N_NODES;

    // zero agg + control block (s2/r are fully overwritten before being read)
    hipMemsetAsync(agg, 0, N_NODES * sizeof(float) + sizeof(Ctl), stream);

    fused<<<N_NODES + GATHER_BLKS, NTHR, 0, stream>>>(
        col, values, adj, src_nodes,
        w1e, b1e, w2e, b2e, w1n, b1n, w2n, b2n,
        agg, s2g, r, ctl, outp);
}